// Round 8
// baseline (129.820 us; speedup 1.0000x reference)
//
#include <hip/hip_runtime.h>
#include <hip/hip_bf16.h>

// DCNv2 forward: B=2, C=256, H=W=96, O=256, K=3x3, stride=1, pad=1, dil=1.
// Pipeline:
//  K1 prep     : no-LDS streaming rewrite (R13):
//                (a) transpose NCHW fp32 -> NHWC bf16: 8 coalesced row-loads ->
//                    pack bf16x8 -> one 16B store per c-octet. No LDS, no sync.
//                (b) weight repack: 16 elem/thread as 2 bf16x8 groups
//                    (8 strided gathers + 1 coalesced 16B store each).
//  K2 dcn_main : EXACT R5 schedule (best measured 55.5us): per tap burst-fill
//                32s x 256ch tile into LDS (1 lgkm barrier), 16 mfma chunks
//                with lookahead-1 register prefetch, XOR-swizzled LDS.
// R13 theory: bench dur_us - dcn_main dur ~= 70us EVERY round -> prep (never in
//   top-5, so <56us) + overhead is as big as dcn_main. prep moves only ~32MB;
//   old version ran 1-elem/thread weight blocks (no ILP) and a 2-phase LDS
//   transpose. Streaming rewrite targets ~8us. Single-variable round: dcn_main
//   untouched (R12 stagger dropped - measured null, 56.5 vs 55.5 = noise).
// Ledger: R6 ILP-deep=60, R8 TLP-2x=58, R9 batch-fuse=78, R10 W-preload=68,
//   R12 stagger=56.5 -- all null-or-worse vs R5=55.5. dcn_main theories spent;
//   attack the other dispatch.

#define Hh 96
#define Ww 96
#define Cc 256
#define Oo 256
#define Bb 2
#define Kk 9
#define Ss (Hh * Ww)          // 9216
#define CKTOT (Cc * Kk)       // 2304

typedef __bf16 bf16x8 __attribute__((ext_vector_type(8)));
typedef float f32x16 __attribute__((ext_vector_type(16)));
typedef float f32x2 __attribute__((ext_vector_type(2)));

__device__ __forceinline__ f32x2 up2(unsigned u) {
  f32x2 r;
  r.x = __uint_as_float(u << 16);
  r.y = __uint_as_float(u & 0xffff0000u);
  return r;
}

// barrier with LDS drain only — prefetched global loads stay in flight.
// simm16 0xC07F = lgkmcnt(0), expcnt(0), vmcnt(63)=no-wait.
__device__ __forceinline__ void barrier_lgkm() {
  asm volatile("" ::: "memory");
  __builtin_amdgcn_s_waitcnt(0xC07F);
  __builtin_amdgcn_s_barrier();
  asm volatile("" ::: "memory");
}

// ---------------- K1: streaming prep (no LDS, no syncthreads) ----------------
// blocks [0,288)   : transpose. block = (b, 64-hw tile). Per thread: for each
//                    of 8 c-octets: 8 coalesced 256B loads + 1 bf16x8 store.
// blocks [288,432) : weight repack to 32x32 A-fragment order:
//   wt[kk][cc][osub][lane][j]: o = osub*32 + (lane&31), ch = cc*16 + (lane>>5)*8 + j
//   16 elements/thread = 2 bf16x8 groups.
__global__ __launch_bounds__(256) void prep(const float* __restrict__ inp,
                                            const float* __restrict__ wsrc,
                                            __bf16* __restrict__ it,
                                            __bf16* __restrict__ wt) {
  const int bx = blockIdx.x;
  const int tid = threadIdx.x;

  if (bx < 288) {
    // ---- transpose NCHW fp32 -> NHWC bf16 ----
    const int b = bx / 144;
    const int hw0 = (bx % 144) * 64;
    const int hw_l = tid & 63;
    const int wv = tid >> 6;  // 0..3
    const float* src = inp + ((size_t)b * Cc) * Ss + hw0 + hw_l;
    __bf16* dst = it + ((size_t)(b * Ss + hw0 + hw_l)) * Cc;
#pragma unroll
    for (int o8 = 0; o8 < 8; ++o8) {
      const int c0 = (wv + o8 * 4) * 8;  // c-octet base
      float v[8];
#pragma unroll
      for (int j = 0; j < 8; ++j) v[j] = src[(size_t)(c0 + j) * Ss];
      bf16x8 r;
#pragma unroll
      for (int j = 0; j < 8; ++j) r[j] = (__bf16)v[j];
      *(bf16x8*)(dst + c0) = r;
    }
  } else {
    // ---- weight repack: 16 consecutive wt elements per thread ----
    const int t = (bx - 288) * 256 + tid;  // t < 36864
#pragma unroll
    for (int g = 0; g < 2; ++g) {
      const int ig = t * 16 + g * 8;       // group base, j = 0..7
      const int l = (ig >> 3) & 63;
      const int osub = (ig >> 9) & 7;
      const int cc = (ig >> 12) & 15;
      const int kk = ig >> 16;
      const int o = osub * 32 + (l & 31);
      const int chb = cc * 16 + ((l >> 5) << 3);
      float v[8];
#pragma unroll
      for (int j = 0; j < 8; ++j)
        v[j] = wsrc[(size_t)(o * Cc + chb + j) * Kk + kk];
      bf16x8 r;
#pragma unroll
      for (int j = 0; j < 8; ++j) r[j] = (__bf16)v[j];
      *(bf16x8*)(wt + ig) = r;
    }
  }
}

// ---------------- K2: fused sample + GEMM (EXACT R5, best measured) ----------------
// grid (288, 2): x = 32-s tile (XCD-swizzled), y = batch.
// 256 thr = 4 waves; wave wv covers o in [wv*64, wv*64+64); block = 32s x 256 O.
__global__ __launch_bounds__(256, 3) void dcn_main(
    const __bf16* __restrict__ it,     // [B][S][C] bf16
    const __bf16* __restrict__ wt,     // 32x32-fragment-order weights
    const float* __restrict__ offset,  // [B][18][S]
    const float* __restrict__ mask,    // [B][9][S]
    const float* __restrict__ bias,    // [O]
    float* __restrict__ out)           // [B][O][S]
{
  __shared__ __bf16 colT[2][32 * 256];  // dbuf tap tile, XOR-swizzled granules
  __shared__ int4 pa9[9][32];           // per-tap corner offsets (elements)
  __shared__ float4 pw9[9][32];         // per-tap corner weights (mask+valid folded)

  const int tid = threadIdx.x;
  // XCD swizzle: XCD j gets 36 contiguous 32-s tiles (~2.6MB L2 working set).
  const int tile = (blockIdx.x & 7) * 36 + (blockIdx.x >> 3);
  const int s0 = tile * 32;
  const int b = blockIdx.y;
  const int lane = tid & 63;
  const int wv = tid >> 6;            // 4 waves -> 64 O each
  const int sB = lane & 31;           // B-frag / C-frag spatial lane
  const int hi = lane >> 5;
  const int fs = tid >> 3;            // fill: s-row 0..31
  const int fg = tid & 7;             // fill: granule group 0..7

  const __bf16* itb = it + (size_t)b * Ss * Cc;

  // ---- bilinear params for all 9 taps up front ----
  for (int idx = tid; idx < 9 * 32; idx += 256) {
    int kk = idx >> 5;
    int sl = idx & 31;
    int s = s0 + sl;
    int ho = s / Ww;
    int wo = s - ho * Ww;
    float dy = offset[((size_t)(b * 18 + 2 * kk)) * Ss + s];
    float dx = offset[((size_t)(b * 18 + 2 * kk + 1)) * Ss + s];
    float m = mask[((size_t)(b * 9 + kk)) * Ss + s];
    float y = (float)(ho - 1 + kk / 3) + dy;
    float x = (float)(wo - 1 + kk % 3) + dx;
    float fy = floorf(y), fx = floorf(x);
    int y0 = (int)fy, x0 = (int)fx;
    float wy = y - fy, wx = x - fx;
    int y1 = y0 + 1, x1 = x0 + 1;
    float vy0 = (y0 >= 0 && y0 < Hh) ? 1.f : 0.f;
    float vy1 = (y1 >= 0 && y1 < Hh) ? 1.f : 0.f;
    float vx0 = (x0 >= 0 && x0 < Ww) ? 1.f : 0.f;
    float vx1 = (x1 >= 0 && x1 < Ww) ? 1.f : 0.f;
    int y0c = min(max(y0, 0), Hh - 1), y1c = min(max(y1, 0), Hh - 1);
    int x0c = min(max(x0, 0), Ww - 1), x1c = min(max(x1, 0), Ww - 1);
    pa9[kk][sl] = make_int4((y0c * Ww + x0c) * Cc, (y0c * Ww + x1c) * Cc,
                            (y1c * Ww + x0c) * Cc, (y1c * Ww + x1c) * Cc);
    pw9[kk][sl] = make_float4(m * (1.f - wy) * (1.f - wx) * vy0 * vx0,
                              m * (1.f - wy) * wx * vy0 * vx1,
                              m * wy * (1.f - wx) * vy1 * vx0,
                              m * wy * wx * vy1 * vx1);
  }
  __syncthreads();

  f32x16 acc0, acc1;
#pragma unroll
  for (int j = 0; j < 16; ++j) { acc0[j] = 0.f; acc1[j] = 0.f; }

  // weight A-fragment load: wt[((kk*16+cc)*8 + osub)*512 + lane*8]
  auto ldW = [&](int kk, int cc, int which) {
    size_t idx = (size_t)((kk * 16 + cc) * 8 + wv * 2 + which);
    return *(const bf16x8*)(wt + (idx << 9) + (lane << 3));
  };
  // B fragment from LDS: row sB, logical granule 2cc+hi, XOR-swizzled
  auto ldB = [&](int buf, int cc) {
    int g = ((2 * cc + hi) ^ (sB & 7)) << 3;
    return *(const bf16x8*)(&colT[buf][sB * 256 + g]);
  };

  for (int kk = 0; kk < Kk; ++kk) {
    const int buf = kk & 1;
    // ---- fill: 16 burst dwordx4 corner loads, bilinear, swizzled LDS write ----
    {
      int4 a = pa9[kk][fs];
      float4 wq = pw9[kk][fs];
      __bf16* drow = &colT[buf][fs * 256];
#pragma unroll
      for (int it2 = 0; it2 < 4; ++it2) {
        int g = fg + it2 * 8;           // logical granule (8 ch)
        const __bf16* p = itb + g * 8;
        uint4 c00 = *(const uint4*)(p + a.x);
        uint4 c01 = *(const uint4*)(p + a.y);
        uint4 c10 = *(const uint4*)(p + a.z);
        uint4 c11 = *(const uint4*)(p + a.w);
        unsigned u0[4] = {c00.x, c00.y, c00.z, c00.w};
        unsigned u1[4] = {c01.x, c01.y, c01.z, c01.w};
        unsigned u2[4] = {c10.x, c10.y, c10.z, c10.w};
        unsigned u3[4] = {c11.x, c11.y, c11.z, c11.w};
        bf16x8 rv;
#pragma unroll
        for (int w = 0; w < 4; ++w) {
          f32x2 r = up2(u0[w]) * wq.x + up2(u1[w]) * wq.y +
                    up2(u2[w]) * wq.z + up2(u3[w]) * wq.w;
          rv[2 * w] = (__bf16)r.x;
          rv[2 * w + 1] = (__bf16)r.y;
        }
        *(bf16x8*)(drow + ((g ^ (fs & 7)) << 3)) = rv;
      }
    }
    // chunk-0 weights issued pre-barrier; lgkm-only barrier keeps them in flight
    bf16x8 Wacur = ldW(kk, 0, 0);
    bf16x8 Wbcur = ldW(kk, 0, 1);
    barrier_lgkm();

    // ---- compute: 16 chunks, register lookahead, no barriers ----
    bf16x8 Bcur = ldB(buf, 0);
#pragma unroll
    for (int cc = 0; cc < 16; ++cc) {
      bf16x8 Bn, Wan, Wbn;
      if (cc < 15) {
        Bn = ldB(buf, cc + 1);
        Wan = ldW(kk, cc + 1, 0);
        Wbn = ldW(kk, cc + 1, 1);
      }
      acc0 = __builtin_amdgcn_mfma_f32_32x32x16_bf16(Wacur, Bcur, acc0, 0, 0, 0);
      acc1 = __builtin_amdgcn_mfma_f32_32x32x16_bf16(Wbcur, Bcur, acc1, 0, 0, 0);
      if (cc < 15) {
        Bcur = Bn;
        Wacur = Wan;
        Wbcur = Wbn;
      }
    }
  }

  // ---- epilogue: direct store with bias ----
  // D mapping (32x32): col(s)=lane&31, row(o-off)=(r&3)+8*(r>>2)+4*(lane>>5)
  float* ob = out + (size_t)b * Oo * Ss + s0 + sB;
#pragma unroll
  for (int os = 0; os < 2; ++os) {
#pragma unroll
    for (int r = 0; r < 16; ++r) {
      int o = wv * 64 + os * 32 + (r & 3) + 8 * (r >> 2) + 4 * hi;
      float v = (os ? acc1[r] : acc0[r]) + bias[o];
      ob[(size_t)o * Ss] = v;
    }
  }
}

extern "C" void kernel_launch(void* const* d_in, const int* in_sizes, int n_in,
                              void* d_out, int out_size, void* d_ws, size_t ws_size,
                              hipStream_t stream) {
  (void)in_sizes; (void)n_in; (void)out_size; (void)ws_size;
  const float* inp = (const float*)d_in[0];
  const float* offset = (const float*)d_in[1];
  const float* mask = (const float*)d_in[2];
  const float* weight = (const float*)d_in[3];
  const float* bias = (const float*)d_in[4];
  float* out = (float*)d_out;

  __bf16* it = (__bf16*)d_ws;                                      // 9,437,184 B
  __bf16* wt = (__bf16*)((char*)d_ws + (size_t)Bb * Ss * Cc * 2);  // 1,179,648 B

  prep<<<432, 256, 0, stream>>>(inp, weight, it, wt);
  dcn_main<<<dim3(288, Bb), 256, 0, stream>>>(it, wt, offset, mask, bias, out);
}